// Round 1
// baseline (198.027 us; speedup 1.0000x reference)
//
#include <hip/hip_runtime.h>
#include <math.h>

#define WPB 4  // waves (rays) per block -> 256 threads

#define NEAR_T   2.0f
#define FAR_T    6.0f
#define EPS_W_C  1e-5f
#define EPS_T_C  1e-10f
#define FAR_DIST 1e10f

__device__ __forceinline__ float tval(int i) {
    // matches linspace(0,1,64): i * (1/63), then NEAR + (FAR-NEAR)*t
    return NEAR_T + (FAR_T - NEAR_T) * ((float)i * (1.0f / 63.0f));
}

__device__ __forceinline__ float softplus_f(float x) {
    // jax.nn.softplus = logaddexp(x, 0) = max(x,0) + log1p(exp(-|x|))
    return fmaxf(x, 0.0f) + log1pf(expf(-fabsf(x)));
}

__device__ __forceinline__ float sigmoid_f(float x) {
    return 1.0f / (1.0f + expf(-x));
}

__device__ __forceinline__ float wave_incl_prod(float f, int lane) {
    float g = f;
#pragma unroll
    for (int s = 1; s < 64; s <<= 1) {
        float o = __shfl_up(g, s);
        if (lane >= s) g *= o;
    }
    return g;
}

__device__ __forceinline__ float wave_incl_sum(float f, int lane) {
    float g = f;
#pragma unroll
    for (int s = 1; s < 64; s <<= 1) {
        float o = __shfl_up(g, s);
        if (lane >= s) g += o;
    }
    return g;
}

__device__ __forceinline__ float wave_sum(float v) {
#pragma unroll
    for (int s = 32; s > 0; s >>= 1) v += __shfl_xor(v, s);
    return v;
}

__global__ __launch_bounds__(WPB * 64)
void volrender_kernel(const float* __restrict__ ro_g,
                      const float* __restrict__ rd_g,
                      const float* __restrict__ Wd_g,
                      const float* __restrict__ Wc_g,
                      float* __restrict__ out, int N) {
    __shared__ float s_cdf[WPB][64];   // inclusive cumsum of pdf
    __shared__ float s_ts[WPB][64];    // importance t_samples (sorted)
    __shared__ float s_m[WPB][128];    // merged fine t values

    const int lane = threadIdx.x & 63;
    const int wid  = threadIdx.x >> 6;
    int ray = blockIdx.x * WPB + wid;
    if (ray >= N) ray = N - 1;  // duplicate work, same writes; keeps barriers uniform

    // ray + field weights (broadcast loads, L1-served)
    const float ox = ro_g[ray * 3 + 0], oy = ro_g[ray * 3 + 1], oz = ro_g[ray * 3 + 2];
    const float dx = rd_g[ray * 3 + 0], dy = rd_g[ray * 3 + 1], dz = rd_g[ray * 3 + 2];
    const float wd0 = Wd_g[0], wd1 = Wd_g[1], wd2 = Wd_g[2];
    float wc[9];
#pragma unroll
    for (int i = 0; i < 9; ++i) wc[i] = Wc_g[i];

    const long Nl = N;
    float* out_rgb  = out;
    float* out_dep  = out + 3 * Nl;
    float* out_acc  = out + 4 * Nl;
    float* out_frgb = out + 5 * Nl;
    float* out_fdep = out + 8 * Nl;
    float* out_facc = out + 9 * Nl;

    // ---------------- coarse pass: lane = sample ----------------
    const float t_c = tval(lane);
    {
        const float px = ox + dx * t_c, py = oy + dy * t_c, pz = oz + dz * t_c;
        const float dd = px * wd0 + py * wd1 + pz * wd2;
        const float sigma = softplus_f(dd);
        const float c0 = sigmoid_f(px * wc[0] + py * wc[3] + pz * wc[6]);
        const float c1 = sigmoid_f(px * wc[1] + py * wc[4] + pz * wc[7]);
        const float c2 = sigmoid_f(px * wc[2] + py * wc[5] + pz * wc[8]);

        const float dist = (lane < 63) ? (tval(lane + 1) - t_c) : FAR_DIST;
        const float alpha = 1.0f - expf(-sigma * dist);
        const float f = 1.0f - alpha + EPS_T_C;
        const float incl = wave_incl_prod(f, lane);
        const float prev = __shfl_up(incl, 1);
        const float trans = (lane == 0) ? 1.0f : prev;
        const float w = alpha * trans;

        const float accw = wave_sum(w);
        const float dep  = wave_sum(w * t_c);
        const float r0   = wave_sum(w * c0);
        const float r1   = wave_sum(w * c1);
        const float r2   = wave_sum(w * c2);
        if (lane == 0) {
            const float bg = 1.0f - accw;
            out_rgb[ray * 3 + 0] = r0 + bg;
            out_rgb[ray * 3 + 1] = r1 + bg;
            out_rgb[ray * 3 + 2] = r2 + bg;
            out_dep[ray] = dep;
            out_acc[ray] = accw;
        }

        // ------------- importance CDF -------------
        const float wp = w + EPS_W_C;
        const float total = wave_sum(wp);
        const float pdf = wp / total;
        s_cdf[wid][lane] = wave_incl_sum(pdf, lane);
    }
    __syncthreads();

    // ------------- inverse-CDF sampling (lane = u index) -------------
    {
        const float u = (float)lane * (1.0f / 63.0f);
        // upper_bound: first index with cdf_incl[i] > u  (cdf[0]=0 handled analytically)
        int lo = 0, hi = 64;
        while (lo < hi) {
            int mid = (lo + hi) >> 1;
            if (s_cdf[wid][mid] <= u) lo = mid + 1; else hi = mid;
        }
        const int below = lo;                 // clip(idx-1,0,64), idx = lo+1
        const int above = min(lo + 1, 64);
        const float cdf0 = (below == 0) ? 0.0f : s_cdf[wid][below - 1];
        const float cdf1 = s_cdf[wid][above - 1];
        const float bin0 = tval(min(below, 63));
        const float bin1 = tval(min(above, 63));
        float denom = cdf1 - cdf0;
        if (denom < EPS_W_C) denom = 1.0f;
        const float tt = (u - cdf0) / denom;
        s_ts[wid][lane] = bin0 + tt * (bin1 - bin0);
    }
    __syncthreads();

    // ------------- merge (both arrays sorted) -------------
    {
        // rank of analytic A[lane] among merged: lane + #{B_j < A[lane]}
        const float av = t_c;
        int lo = 0, hi = 64;
        while (lo < hi) {
            int mid = (lo + hi) >> 1;
            if (s_ts[wid][mid] < av) lo = mid + 1; else hi = mid;
        }
        const int rankA = lane + lo;
        // rank of B[lane]: lane + #{A_i <= B[lane]} (search analytic values, exact same fp formula)
        const float bv = s_ts[wid][lane];
        lo = 0; hi = 64;
        while (lo < hi) {
            int mid = (lo + hi) >> 1;
            if (tval(mid) <= bv) lo = mid + 1; else hi = mid;
        }
        const int rankB = lane + lo;
        s_m[wid][rankA] = av;
        s_m[wid][rankB] = bv;
    }
    __syncthreads();

    // ---------------- fine pass: 128 samples, 2 per lane ----------------
    {
        float accw = 0.0f, dep = 0.0f, r0 = 0.0f, r1 = 0.0f, r2 = 0.0f;
        float carry = 1.0f;
#pragma unroll
        for (int h = 0; h < 2; ++h) {
            const int e = h * 64 + lane;
            const float t = s_m[wid][e];
            const float dist = (e < 127) ? (s_m[wid][e + 1] - t) : FAR_DIST;

            const float px = ox + dx * t, py = oy + dy * t, pz = oz + dz * t;
            const float dd = px * wd0 + py * wd1 + pz * wd2;
            const float sigma = softplus_f(dd);
            const float c0 = sigmoid_f(px * wc[0] + py * wc[3] + pz * wc[6]);
            const float c1 = sigmoid_f(px * wc[1] + py * wc[4] + pz * wc[7]);
            const float c2 = sigmoid_f(px * wc[2] + py * wc[5] + pz * wc[8]);

            const float alpha = 1.0f - expf(-sigma * dist);
            const float f = 1.0f - alpha + EPS_T_C;
            const float incl = wave_incl_prod(f, lane);
            const float prev = __shfl_up(incl, 1);
            const float trans = carry * ((lane == 0) ? 1.0f : prev);
            const float w = alpha * trans;

            accw += w;
            dep  += w * t;
            r0   += w * c0;
            r1   += w * c1;
            r2   += w * c2;
            carry *= __shfl(incl, 63);
        }
        accw = wave_sum(accw);
        dep  = wave_sum(dep);
        r0   = wave_sum(r0);
        r1   = wave_sum(r1);
        r2   = wave_sum(r2);
        if (lane == 0) {
            const float bg = 1.0f - accw;
            out_frgb[ray * 3 + 0] = r0 + bg;
            out_frgb[ray * 3 + 1] = r1 + bg;
            out_frgb[ray * 3 + 2] = r2 + bg;
            out_fdep[ray] = dep;
            out_facc[ray] = accw;
        }
    }
}

extern "C" void kernel_launch(void* const* d_in, const int* in_sizes, int n_in,
                              void* d_out, int out_size, void* d_ws, size_t ws_size,
                              hipStream_t stream) {
    const float* ro = (const float*)d_in[0];
    const float* rd = (const float*)d_in[1];
    // d_in[2] exposure_values, d_in[5] appearance_ids: unused by reference
    const float* Wd = (const float*)d_in[3];
    const float* Wc = (const float*)d_in[4];
    float* out = (float*)d_out;

    const int N = in_sizes[0] / 3;
    const int grid = (N + WPB - 1) / WPB;
    volrender_kernel<<<grid, WPB * 64, 0, stream>>>(ro, rd, Wd, Wc, out, N);
}

// Round 3
// 146.551 us; speedup vs baseline: 1.3513x; 1.3513x over previous
//
#include <hip/hip_runtime.h>
#include <math.h>

#define WPB 4  // waves (rays) per block -> 256 threads

#define NEAR_T   2.0f
#define FAR_T    6.0f
#define EPS_W_C  1e-5f
#define EPS_T_C  1e-10f
#define FAR_DIST 1e10f

__device__ __forceinline__ float tval(int i) {
    // matches linspace(0,1,64): i * (1/63), then NEAR + (FAR-NEAR)*t
    return NEAR_T + (FAR_T - NEAR_T) * ((float)i * (1.0f / 63.0f));
}

__device__ __forceinline__ float rcp_fast(float x) {
    return __builtin_amdgcn_rcpf(x);   // v_rcp_f32, ~1 ulp
}

__device__ __forceinline__ float softplus_f(float x) {
    // jax.nn.softplus = max(x,0) + log1p(exp(-|x|)).
    // MUST preserve tiny log1p values: sigma as small as 1e-13 still saturates
    // alpha on the last sample (dist = 1e10). __logf(1+e) rounds 1+e to 1.0f
    // for e < 2^-24 -> catastrophic (R2 failure). Two-path log1p:
    const float e = __expf(-fabsf(x));
    const float big   = __logf(1.0f + e);                          // e > 2^-7: abs err ~6e-8, alpha saturates anyway
    const float small = e * (1.0f - e * (0.5f - e * 0.33333334f)); // e <= 2^-7: rel err ~1e-7, preserves tiny e
    return fmaxf(x, 0.0f) + ((e > 0.0078125f) ? big : small);
}

__device__ __forceinline__ float sigmoid_f(float x) {
    return rcp_fast(1.0f + __expf(-x));
}

__device__ __forceinline__ float wave_incl_prod(float f, int lane) {
    float g = f;
#pragma unroll
    for (int s = 1; s < 64; s <<= 1) {
        float o = __shfl_up(g, s);
        if (lane >= s) g *= o;
    }
    return g;
}

__device__ __forceinline__ float wave_incl_sum(float f, int lane) {
    float g = f;
#pragma unroll
    for (int s = 1; s < 64; s <<= 1) {
        float o = __shfl_up(g, s);
        if (lane >= s) g += o;
    }
    return g;
}

__device__ __forceinline__ float wave_sum(float v) {
#pragma unroll
    for (int s = 32; s > 0; s >>= 1) v += __shfl_xor(v, s);
    return v;
}

__global__ __launch_bounds__(WPB * 64)
void volrender_kernel(const float* __restrict__ ro_g,
                      const float* __restrict__ rd_g,
                      const float* __restrict__ Wd_g,
                      const float* __restrict__ Wc_g,
                      float* __restrict__ out, int N) {
    __shared__ float s_cdf[WPB][64];   // inclusive cumsum of pdf
    __shared__ float s_ts[WPB][64];    // importance t_samples (sorted)
    __shared__ float s_m[WPB][128];    // merged fine t values

    const int lane = threadIdx.x & 63;
    const int wid  = threadIdx.x >> 6;
    int ray = blockIdx.x * WPB + wid;
    if (ray >= N) ray = N - 1;  // duplicate work, same writes; keeps barriers uniform

    // ray + field weights (broadcast loads, L1-served)
    const float ox = ro_g[ray * 3 + 0], oy = ro_g[ray * 3 + 1], oz = ro_g[ray * 3 + 2];
    const float dx = rd_g[ray * 3 + 0], dy = rd_g[ray * 3 + 1], dz = rd_g[ray * 3 + 2];
    const float wd0 = Wd_g[0], wd1 = Wd_g[1], wd2 = Wd_g[2];
    float wc[9];
#pragma unroll
    for (int i = 0; i < 9; ++i) wc[i] = Wc_g[i];

    const long Nl = N;
    float* out_rgb  = out;
    float* out_dep  = out + 3 * Nl;
    float* out_acc  = out + 4 * Nl;
    float* out_frgb = out + 5 * Nl;
    float* out_fdep = out + 8 * Nl;
    float* out_facc = out + 9 * Nl;

    // ---------------- coarse pass: lane = sample ----------------
    const float t_c = tval(lane);
    {
        const float px = ox + dx * t_c, py = oy + dy * t_c, pz = oz + dz * t_c;
        const float dd = px * wd0 + py * wd1 + pz * wd2;
        const float sigma = softplus_f(dd);
        const float c0 = sigmoid_f(px * wc[0] + py * wc[3] + pz * wc[6]);
        const float c1 = sigmoid_f(px * wc[1] + py * wc[4] + pz * wc[7]);
        const float c2 = sigmoid_f(px * wc[2] + py * wc[5] + pz * wc[8]);

        const float dist = (lane < 63) ? (tval(lane + 1) - t_c) : FAR_DIST;
        const float alpha = 1.0f - __expf(-sigma * dist);
        const float f = 1.0f - alpha + EPS_T_C;
        const float incl = wave_incl_prod(f, lane);
        const float prev = __shfl_up(incl, 1);
        const float trans = (lane == 0) ? 1.0f : prev;
        const float w = alpha * trans;

        const float accw = wave_sum(w);
        const float dep  = wave_sum(w * t_c);
        const float r0   = wave_sum(w * c0);
        const float r1   = wave_sum(w * c1);
        const float r2   = wave_sum(w * c2);
        if (lane == 0) {
            const float bg = 1.0f - accw;
            out_rgb[ray * 3 + 0] = r0 + bg;
            out_rgb[ray * 3 + 1] = r1 + bg;
            out_rgb[ray * 3 + 2] = r2 + bg;
            out_dep[ray] = dep;
            out_acc[ray] = accw;
        }

        // ------------- importance CDF -------------
        const float wp = w + EPS_W_C;
        const float total = wave_sum(wp);
        const float inv_total = rcp_fast(total);
        const float pdf = wp * inv_total;
        s_cdf[wid][lane] = wave_incl_sum(pdf, lane);
    }
    __syncthreads();

    // ------------- inverse-CDF sampling (lane = u index) -------------
    {
        const float u = (float)lane * (1.0f / 63.0f);
        // upper_bound: first index with cdf_incl[i] > u  (cdf[0]=0 handled analytically)
        int lo = 0, hi = 64;
        while (lo < hi) {
            int mid = (lo + hi) >> 1;
            if (s_cdf[wid][mid] <= u) lo = mid + 1; else hi = mid;
        }
        const int below = lo;                 // clip(idx-1,0,64), idx = lo+1
        const int above = min(lo + 1, 64);
        const float cdf0 = (below == 0) ? 0.0f : s_cdf[wid][below - 1];
        const float cdf1 = s_cdf[wid][above - 1];
        const float bin0 = tval(min(below, 63));
        const float bin1 = tval(min(above, 63));
        float denom = cdf1 - cdf0;
        if (denom < EPS_W_C) denom = 1.0f;
        const float tt = (u - cdf0) * rcp_fast(denom);
        s_ts[wid][lane] = bin0 + tt * (bin1 - bin0);
    }
    __syncthreads();

    // ------------- merge (both arrays sorted) -------------
    {
        // rank of analytic A[lane] among merged: lane + #{B_j < A[lane]}
        const float av = t_c;
        int lo = 0, hi = 64;
        while (lo < hi) {
            int mid = (lo + hi) >> 1;
            if (s_ts[wid][mid] < av) lo = mid + 1; else hi = mid;
        }
        const int rankA = lane + lo;
        // rank of B[lane]: lane + #{A_i <= B[lane]} (search analytic values, exact same fp formula)
        const float bv = s_ts[wid][lane];
        lo = 0; hi = 64;
        while (lo < hi) {
            int mid = (lo + hi) >> 1;
            if (tval(mid) <= bv) lo = mid + 1; else hi = mid;
        }
        const int rankB = lane + lo;
        s_m[wid][rankA] = av;
        s_m[wid][rankB] = bv;
    }
    __syncthreads();

    // ---------------- fine pass: 128 samples, 2 per lane ----------------
    {
        float accw = 0.0f, dep = 0.0f, r0 = 0.0f, r1 = 0.0f, r2 = 0.0f;
        float carry = 1.0f;
#pragma unroll
        for (int h = 0; h < 2; ++h) {
            const int e = h * 64 + lane;
            const float t = s_m[wid][e];
            const float dist = (e < 127) ? (s_m[wid][e + 1] - t) : FAR_DIST;

            const float px = ox + dx * t, py = oy + dy * t, pz = oz + dz * t;
            const float dd = px * wd0 + py * wd1 + pz * wd2;
            const float sigma = softplus_f(dd);
            const float c0 = sigmoid_f(px * wc[0] + py * wc[3] + pz * wc[6]);
            const float c1 = sigmoid_f(px * wc[1] + py * wc[4] + pz * wc[7]);
            const float c2 = sigmoid_f(px * wc[2] + py * wc[5] + pz * wc[8]);

            const float alpha = 1.0f - __expf(-sigma * dist);
            const float f = 1.0f - alpha + EPS_T_C;
            const float incl = wave_incl_prod(f, lane);
            const float prev = __shfl_up(incl, 1);
            const float trans = carry * ((lane == 0) ? 1.0f : prev);
            const float w = alpha * trans;

            accw += w;
            dep  += w * t;
            r0   += w * c0;
            r1   += w * c1;
            r2   += w * c2;
            carry *= __shfl(incl, 63);
        }
        accw = wave_sum(accw);
        dep  = wave_sum(dep);
        r0   = wave_sum(r0);
        r1   = wave_sum(r1);
        r2   = wave_sum(r2);
        if (lane == 0) {
            const float bg = 1.0f - accw;
            out_frgb[ray * 3 + 0] = r0 + bg;
            out_frgb[ray * 3 + 1] = r1 + bg;
            out_frgb[ray * 3 + 2] = r2 + bg;
            out_fdep[ray] = dep;
            out_facc[ray] = accw;
        }
    }
}

extern "C" void kernel_launch(void* const* d_in, const int* in_sizes, int n_in,
                              void* d_out, int out_size, void* d_ws, size_t ws_size,
                              hipStream_t stream) {
    const float* ro = (const float*)d_in[0];
    const float* rd = (const float*)d_in[1];
    // d_in[2] exposure_values, d_in[5] appearance_ids: unused by reference
    const float* Wd = (const float*)d_in[3];
    const float* Wc = (const float*)d_in[4];
    float* out = (float*)d_out;

    const int N = in_sizes[0] / 3;
    const int grid = (N + WPB - 1) / WPB;
    volrender_kernel<<<grid, WPB * 64, 0, stream>>>(ro, rd, Wd, Wc, out, N);
}

// Round 4
// 103.648 us; speedup vs baseline: 1.9106x; 1.4139x over previous
//
#include <hip/hip_runtime.h>
#include <math.h>

#define WPB 4  // waves (rays) per block -> 256 threads

#define NEAR_T   2.0f
#define FAR_T    6.0f
#define EPS_W_C  1e-5f
#define EPS_T_C  1e-10f
#define FAR_DIST 1e10f

__device__ __forceinline__ float tval(int i) {
    // matches linspace(0,1,64): i * (1/63), then NEAR + (FAR-NEAR)*t
    return NEAR_T + (FAR_T - NEAR_T) * ((float)i * (1.0f / 63.0f));
}

__device__ __forceinline__ float rcp_fast(float x) {
    return __builtin_amdgcn_rcpf(x);   // v_rcp_f32, ~1 ulp
}

__device__ __forceinline__ float softplus_f(float x) {
    // jax.nn.softplus = max(x,0) + log1p(exp(-|x|)).
    // Two-path log1p: must preserve tiny values (sigma ~1e-13 still saturates
    // alpha at dist=1e10 — R2 failure was __logf(1+e) rounding 1+e -> 1).
    const float e = __expf(-fabsf(x));
    const float big   = __logf(1.0f + e);                          // e > 2^-7
    const float small = e * (1.0f - e * (0.5f - e * 0.33333334f)); // e <= 2^-7, rel err ~1e-7
    return fmaxf(x, 0.0f) + ((e > 0.0078125f) ? big : small);
}

__device__ __forceinline__ float sigmoid_f(float x) {
    return rcp_fast(1.0f + __expf(-x));
}

// ---- DPP cross-lane (VALU pipe, no ds_bpermute) ----
template<int CTRL, int MASK>
__device__ __forceinline__ float dpp_f(float x, float old) {
    return __int_as_float(__builtin_amdgcn_update_dpp(
        __float_as_int(old), __float_as_int(x), CTRL, MASK, 0xF, false));
}

// canonical gfx9 wave64 inclusive scan: row_shr 1/2/4/8, bcast15->rows{1,3}, bcast31->rows{2,3}
__device__ __forceinline__ float scan_incl_add(float x) {
    x += dpp_f<0x111, 0xF>(x, 0.0f);
    x += dpp_f<0x112, 0xF>(x, 0.0f);
    x += dpp_f<0x114, 0xF>(x, 0.0f);
    x += dpp_f<0x118, 0xF>(x, 0.0f);
    x += dpp_f<0x142, 0xA>(x, 0.0f);   // row_bcast15
    x += dpp_f<0x143, 0xC>(x, 0.0f);   // row_bcast31
    return x;
}

__device__ __forceinline__ float scan_incl_mul(float x) {
    x *= dpp_f<0x111, 0xF>(x, 1.0f);
    x *= dpp_f<0x112, 0xF>(x, 1.0f);
    x *= dpp_f<0x114, 0xF>(x, 1.0f);
    x *= dpp_f<0x118, 0xF>(x, 1.0f);
    x *= dpp_f<0x142, 0xA>(x, 1.0f);
    x *= dpp_f<0x143, 0xC>(x, 1.0f);
    return x;
}

__device__ __forceinline__ float excl_shift1(float x, float ident) {
    return dpp_f<0x138, 0xF>(x, ident);  // wave_shr1: lane i <- lane i-1, lane0 <- ident
}

__device__ __forceinline__ float bcast63(float x) {
    return __int_as_float(__builtin_amdgcn_readlane(__float_as_int(x), 63));
}

__device__ __forceinline__ float wave_total(float x) {
    return bcast63(scan_incl_add(x));
}

__global__ __launch_bounds__(WPB * 64)
void volrender_kernel(const float* __restrict__ ro_g,
                      const float* __restrict__ rd_g,
                      const float* __restrict__ Wd_g,
                      const float* __restrict__ Wc_g,
                      float* __restrict__ out, int N) {
    __shared__ float  s_cdf[WPB][64];   // inclusive cumsum of pdf
    __shared__ float  s_ts[WPB][64];    // importance t_samples (sorted)
    __shared__ float  s_m[WPB][128];    // merged fine t values
    __shared__ float4 s_f[WPB][128];    // cached (sigma, c0, c1, c2) per merged sample

    const int lane = threadIdx.x & 63;
    const int wid  = threadIdx.x >> 6;
    int ray = blockIdx.x * WPB + wid;
    if (ray >= N) ray = N - 1;  // duplicate work, same writes; keeps barriers uniform

    const float ox = ro_g[ray * 3 + 0], oy = ro_g[ray * 3 + 1], oz = ro_g[ray * 3 + 2];
    const float dx = rd_g[ray * 3 + 0], dy = rd_g[ray * 3 + 1], dz = rd_g[ray * 3 + 2];
    const float wd0 = Wd_g[0], wd1 = Wd_g[1], wd2 = Wd_g[2];
    float wc[9];
#pragma unroll
    for (int i = 0; i < 9; ++i) wc[i] = Wc_g[i];

    const long Nl = N;
    float* out_rgb  = out;
    float* out_dep  = out + 3 * Nl;
    float* out_acc  = out + 4 * Nl;
    float* out_frgb = out + 5 * Nl;
    float* out_fdep = out + 8 * Nl;
    float* out_facc = out + 9 * Nl;

    // ---------------- coarse pass: lane = sample ----------------
    const float t_c = tval(lane);
    float sig_c, c0_c, c1_c, c2_c;  // cached for fine pass (bit-identical reuse)
    {
        const float px = ox + dx * t_c, py = oy + dy * t_c, pz = oz + dz * t_c;
        const float dd = px * wd0 + py * wd1 + pz * wd2;
        sig_c = softplus_f(dd);
        c0_c = sigmoid_f(px * wc[0] + py * wc[3] + pz * wc[6]);
        c1_c = sigmoid_f(px * wc[1] + py * wc[4] + pz * wc[7]);
        c2_c = sigmoid_f(px * wc[2] + py * wc[5] + pz * wc[8]);

        const float dist = (lane < 63) ? (tval(lane + 1) - t_c) : FAR_DIST;
        const float alpha = 1.0f - __expf(-sig_c * dist);
        const float f = 1.0f - alpha + EPS_T_C;
        const float incl = scan_incl_mul(f);
        const float trans = excl_shift1(incl, 1.0f);
        const float w = alpha * trans;

        const float accw = wave_total(w);
        const float dep  = wave_total(w * t_c);
        const float r0   = wave_total(w * c0_c);
        const float r1   = wave_total(w * c1_c);
        const float r2   = wave_total(w * c2_c);
        if (lane == 0) {
            const float bg = 1.0f - accw;
            out_rgb[ray * 3 + 0] = r0 + bg;
            out_rgb[ray * 3 + 1] = r1 + bg;
            out_rgb[ray * 3 + 2] = r2 + bg;
            out_dep[ray] = dep;
            out_acc[ray] = accw;
        }

        // importance CDF
        const float wp = w + EPS_W_C;
        const float total = wave_total(wp);
        const float pdf = wp * rcp_fast(total);
        s_cdf[wid][lane] = scan_incl_add(pdf);
    }
    __syncthreads();

    // ------------- inverse-CDF sampling (lane = u index) -------------
    float bv;  // this lane's importance t_sample (kept in register)
    {
        const float u = (float)lane * (1.0f / 63.0f);
        int lo = 0, hi = 64;
        while (lo < hi) {
            int mid = (lo + hi) >> 1;
            if (s_cdf[wid][mid] <= u) lo = mid + 1; else hi = mid;
        }
        const int below = lo;                 // clip(idx-1,0,64), idx = lo+1
        const int above = min(lo + 1, 64);
        const float cdf0 = (below == 0) ? 0.0f : s_cdf[wid][below - 1];
        const float cdf1 = s_cdf[wid][above - 1];
        const float bin0 = tval(min(below, 63));
        const float bin1 = tval(min(above, 63));
        float denom = cdf1 - cdf0;
        if (denom < EPS_W_C) denom = 1.0f;
        const float tt = (u - cdf0) * rcp_fast(denom);
        bv = bin0 + tt * (bin1 - bin0);
        s_ts[wid][lane] = bv;
    }
    __syncthreads();

    // ------------- merge ranks + field eval at importance samples -------------
    {
        // rank of analytic A[lane]: lane + #{B_j < A[lane]}
        const float av = t_c;
        int lo = 0, hi = 64;
        while (lo < hi) {
            int mid = (lo + hi) >> 1;
            if (s_ts[wid][mid] < av) lo = mid + 1; else hi = mid;
        }
        const int rankA = lane + lo;
        // rank of B[lane]: lane + #{A_i <= B[lane]} (analytic values, identical fp formula)
        lo = 0; hi = 64;
        while (lo < hi) {
            int mid = (lo + hi) >> 1;
            if (tval(mid) <= bv) lo = mid + 1; else hi = mid;
        }
        const int rankB = lane + lo;

        // evaluate field at the importance sample (the only fresh eval in the fine pass)
        const float px = ox + dx * bv, py = oy + dy * bv, pz = oz + dz * bv;
        const float dd = px * wd0 + py * wd1 + pz * wd2;
        const float sigb = softplus_f(dd);
        const float b0 = sigmoid_f(px * wc[0] + py * wc[3] + pz * wc[6]);
        const float b1 = sigmoid_f(px * wc[1] + py * wc[4] + pz * wc[7]);
        const float b2 = sigmoid_f(px * wc[2] + py * wc[5] + pz * wc[8]);

        s_m[wid][rankA] = av;
        s_m[wid][rankB] = bv;
        s_f[wid][rankA] = make_float4(sig_c, c0_c, c1_c, c2_c);
        s_f[wid][rankB] = make_float4(sigb, b0, b1, b2);
    }
    __syncthreads();

    // ---------------- fine composite: 128 samples, 2 per lane ----------------
    {
        float accw = 0.0f, dep = 0.0f, r0 = 0.0f, r1 = 0.0f, r2 = 0.0f;
        float carry = 1.0f;
#pragma unroll
        for (int h = 0; h < 2; ++h) {
            const int e = h * 64 + lane;
            const float t  = s_m[wid][e];
            const float tn = s_m[wid][min(e + 1, 127)];
            const float dist = (e < 127) ? (tn - t) : FAR_DIST;

            const float4 fv = s_f[wid][e];
            const float alpha = 1.0f - __expf(-fv.x * dist);
            const float f = 1.0f - alpha + EPS_T_C;
            const float incl = scan_incl_mul(f);
            const float trans = carry * excl_shift1(incl, 1.0f);
            const float w = alpha * trans;

            accw += w;
            dep  += w * t;
            r0   += w * fv.y;
            r1   += w * fv.z;
            r2   += w * fv.w;
            carry *= bcast63(incl);
        }
        accw = wave_total(accw);
        dep  = wave_total(dep);
        r0   = wave_total(r0);
        r1   = wave_total(r1);
        r2   = wave_total(r2);
        if (lane == 0) {
            const float bg = 1.0f - accw;
            out_frgb[ray * 3 + 0] = r0 + bg;
            out_frgb[ray * 3 + 1] = r1 + bg;
            out_frgb[ray * 3 + 2] = r2 + bg;
            out_fdep[ray] = dep;
            out_facc[ray] = accw;
        }
    }
}

extern "C" void kernel_launch(void* const* d_in, const int* in_sizes, int n_in,
                              void* d_out, int out_size, void* d_ws, size_t ws_size,
                              hipStream_t stream) {
    const float* ro = (const float*)d_in[0];
    const float* rd = (const float*)d_in[1];
    // d_in[2] exposure_values, d_in[5] appearance_ids: unused by reference
    const float* Wd = (const float*)d_in[3];
    const float* Wc = (const float*)d_in[4];
    float* out = (float*)d_out;

    const int N = in_sizes[0] / 3;
    const int grid = (N + WPB - 1) / WPB;
    volrender_kernel<<<grid, WPB * 64, 0, stream>>>(ro, rd, Wd, Wc, out, N);
}